// Round 16
// baseline (160.200 us; speedup 1.0000x reference)
//
#include <hip/hip_runtime.h>
#include <hip/hip_bf16.h>
#include <stdint.h>

typedef unsigned short u16;
typedef __attribute__((ext_vector_type(8))) __bf16 bf16x8;
typedef __attribute__((ext_vector_type(4))) float f32x4;
typedef __attribute__((ext_vector_type(16))) float f32x16;
typedef __attribute__((ext_vector_type(8))) u16 u16x8;

__device__ __forceinline__ u16 f2bf(float f) {
  union { float f; unsigned int u; } v; v.f = f;
  unsigned int r = v.u + 0x7fffu + ((v.u >> 16) & 1u);
  return (u16)(r >> 16);
}
__device__ __forceinline__ unsigned pack2(float lo, float hi) {
  return (unsigned)f2bf(lo) | ((unsigned)f2bf(hi) << 16);
}

__device__ __forceinline__ f32x4 mfma16(bf16x8 a, bf16x8 b, f32x4 c) {
  return __builtin_amdgcn_mfma_f32_16x16x32_bf16(a, b, c, 0, 0, 0);
}
__device__ __forceinline__ f32x16 mfma32(bf16x8 a, bf16x8 b, f32x16 c) {
  return __builtin_amdgcn_mfma_f32_32x32x16_bf16(a, b, c, 0, 0, 0);
}

__device__ __forceinline__ void gload16(const void* g, void* l) {
  __builtin_amdgcn_global_load_lds((const __attribute__((address_space(1))) void*)g,
                                   (__attribute__((address_space(3))) void*)l,
                                   16, 0, 0);
}

// ---------------- elementwise cast fp32 -> bf16 ----------------
__global__ void cast_bf16_kernel(const float* __restrict__ in, u16* __restrict__ out, int n) {
  int i = (blockIdx.x * 256 + threadIdx.x) * 8;
  if (i >= n) return;
  const float4* p = (const float4*)(in + i);
  float4 a = p[0], b = p[1];
  u16x8 o;
  o[0] = f2bf(a.x); o[1] = f2bf(a.y); o[2] = f2bf(a.z); o[3] = f2bf(a.w);
  o[4] = f2bf(b.x); o[5] = f2bf(b.y); o[6] = f2bf(b.z); o[7] = f2bf(b.w);
  *(u16x8*)(out + i) = o;
}

// ---------------- transpose + cast: in[R][C] fp32 -> out[C][R] bf16 ----------------
__global__ void transpose_cast_k(const float* __restrict__ in, u16* __restrict__ out,
                                 int R, int Ccols) {
  __shared__ float tile[64][65];
  const int c0 = (int)blockIdx.x << 6, r0 = (int)blockIdx.y << 6;
  const int tx = threadIdx.x & 63, ty = threadIdx.x >> 6;
#pragma unroll
  for (int i = ty; i < 64; i += 4)
    tile[i][tx] = in[(size_t)(r0 + i) * Ccols + c0 + tx];
  __syncthreads();
#pragma unroll
  for (int i = ty; i < 64; i += 4)
    out[(size_t)(c0 + i) * R + r0 + tx] = f2bf(tile[tx][i]);
}

// ---------------- QKV GEMM, BK=64, fused bias+RoPE+head-split epilogue ----------------
// V section writes chunked-transposed vtc[bh][ch][64 d][64 s] directly (R14).
__global__ __launch_bounds__(256, 3)
void gemm_qkv(const u16* __restrict__ A, const u16* __restrict__ Bt,
              const float* __restrict__ bias,
              const float* __restrict__ fc, const float* __restrict__ fs,
              u16* __restrict__ qr, u16* __restrict__ kr, u16* __restrict__ vtc) {
  const int K = 1024;
  __shared__ __align__(16) u16 smem[128 * 136];
  u16* const As = smem;
  u16* const Bs = smem + 8192;
  const int m0 = (int)(blockIdx.x / 24) << 7;
  const int n0 = (int)(blockIdx.x % 24) << 7;
  const int tid = threadIdx.x;
  const int l = tid & 63, lg = l >> 4, ll = l & 15;
  const int w = tid >> 6;
  const int wr = (w >> 1) << 6, wc = (w & 1) << 6;
  const int srow = tid >> 2, scol = (tid & 3) << 3;
  const u16* ga = A + (size_t)(m0 + srow) * K + scol;
  const u16* gb = Bt + (size_t)(n0 + srow) * K + scol;
  const size_t K64 = (size_t)64 * K;
  u16* const la00 = &As[srow * 32 + scol];
  u16* const la01 = &As[4096 + srow * 32 + scol];
  u16* const la10 = &As[(srow + 64) * 32 + scol];
  u16* const la11 = &As[4096 + (srow + 64) * 32 + scol];
  u16* const lb00 = &Bs[srow * 32 + scol];
  u16* const lb01 = &Bs[4096 + srow * 32 + scol];
  u16* const lb10 = &Bs[(srow + 64) * 32 + scol];
  u16* const lb11 = &Bs[4096 + (srow + 64) * 32 + scol];
  f32x4 acc[4][4] = {};
  for (int kt = 0; kt < K; kt += 64) {
    gload16(ga + kt, la00);       gload16(ga + kt + 32, la01);
    gload16(ga + kt + K64, la10); gload16(ga + kt + K64 + 32, la11);
    gload16(gb + kt, lb00);       gload16(gb + kt + 32, lb01);
    gload16(gb + kt + K64, lb10); gload16(gb + kt + K64 + 32, lb11);
    __syncthreads();
#pragma unroll
    for (int h = 0; h < 2; ++h) {
      bf16x8 a[4], b[4];
#pragma unroll
      for (int i = 0; i < 4; ++i) {
        a[i] = *(const bf16x8*)&As[h * 4096 + (wr + i * 16 + ll) * 32 + lg * 8];
        b[i] = *(const bf16x8*)&Bs[h * 4096 + (wc + i * 16 + ll) * 32 + lg * 8];
      }
#pragma unroll
      for (int mi = 0; mi < 4; ++mi)
#pragma unroll
        for (int ni = 0; ni < 4; ++ni)
          acc[mi][ni] = mfma16(a[mi], b[ni], acc[mi][ni]);
    }
    __syncthreads();
  }
  const int sec = n0 >> 10;
  const int h0 = (n0 & 1023) >> 6;
#pragma unroll
  for (int ni = 0; ni < 4; ++ni) {
    const int cc = wc + ni * 16 + ll;
    const int n = n0 + cc;
    const int d = n & 63;
    const float bi_ = bias[n];
    const int i2 = d >> 1;
    const bool odd = d & 1;
#pragma unroll
    for (int mi = 0; mi < 4; ++mi) {
#pragma unroll
      for (int r = 0; r < 4; ++r) {
        const int rr = wr + mi * 16 + lg * 4 + r;
        const int s = (m0 + rr) & 2047;
        float v = acc[mi][ni][r] + bi_;
        if (sec < 2) {
          const float c = fc[s * 32 + i2], sn = fs[s * 32 + i2];
          const float p = __shfl_xor(v, 1);
          v = odd ? (p * sn + v * c) : (v * c - p * sn);
          if (sec == 0) v *= 0.125f;
          smem[rr * 136 + cc] = f2bf(v);
        } else {
          smem[cc * 136 + rr] = f2bf(v);
        }
      }
    }
  }
  __syncthreads();
  if (sec < 2) {
    u16* const dst = (sec == 0) ? qr : kr;
#pragma unroll
    for (int it = 0; it < 8; ++it) {
      const int c = it * 256 + tid;
      const int j = c & 7, hh = (c >> 3) & 1, rr = c >> 4;
      const int row = m0 + rr;
      const int bb = row >> 11, ss = row & 2047;
      const uint4 val = *(const uint4*)&smem[rr * 136 + hh * 64 + j * 8];
      *(uint4*)&dst[((size_t)(((bb << 4) + h0 + hh) << 11) + ss) * 64 + j * 8] = val;
    }
  } else {
    const int b16 = (m0 >> 11) << 4;
    const int chbase = (m0 & 2047) >> 6;
#pragma unroll
    for (int it = 0; it < 8; ++it) {
      const int c = it * 256 + tid;
      const int j2 = c & 7;
      const int rr2 = c >> 3;
      const int d = rr2 & 63, hh = (rr2 >> 6) & 1, chk = rr2 >> 7;
      const uint4 val = *(const uint4*)&smem[(hh * 64 + d) * 136 + chk * 64 + j2 * 8];
      *(uint4*)&vtc[(((size_t)(b16 + h0 + hh)) * 32 + chbase + chk) * 4096 + d * 64 + j2 * 8] = val;
    }
  }
}

// ---------------- GEMM (O-proj): BK=64, fp32 out ----------------
__global__ __launch_bounds__(256, 2)
void gemm_bt(const u16* __restrict__ A, const u16* __restrict__ Bt,
             const float* __restrict__ bias, float* __restrict__ C,
             int M, int N, int K) {
  __shared__ __align__(16) u16 As[2 * 128 * 32];
  __shared__ __align__(16) u16 Bs[2 * 128 * 32];
  const int nb = N >> 7;
  const int m0 = (int)(blockIdx.x / nb) << 7;
  const int n0 = (int)(blockIdx.x % nb) << 7;
  const int tid = threadIdx.x;
  const int l = tid & 63, lg = l >> 4, ll = l & 15;
  const int w = tid >> 6;
  const int wr = (w >> 1) << 6, wc = (w & 1) << 6;
  const int srow = tid >> 2, scol = (tid & 3) << 3;
  const u16* ga = A + (size_t)(m0 + srow) * K + scol;
  const u16* gb = Bt + (size_t)(n0 + srow) * K + scol;
  const size_t K64 = (size_t)64 * K;
  u16* const la00 = &As[srow * 32 + scol];
  u16* const la01 = &As[4096 + srow * 32 + scol];
  u16* const la10 = &As[(srow + 64) * 32 + scol];
  u16* const la11 = &As[4096 + (srow + 64) * 32 + scol];
  u16* const lb00 = &Bs[srow * 32 + scol];
  u16* const lb01 = &Bs[4096 + srow * 32 + scol];
  u16* const lb10 = &Bs[(srow + 64) * 32 + scol];
  u16* const lb11 = &Bs[4096 + (srow + 64) * 32 + scol];
  f32x4 acc[4][4] = {};
  for (int kt = 0; kt < K; kt += 64) {
    gload16(ga + kt, la00);       gload16(ga + kt + 32, la01);
    gload16(ga + kt + K64, la10); gload16(ga + kt + K64 + 32, la11);
    gload16(gb + kt, lb00);       gload16(gb + kt + 32, lb01);
    gload16(gb + kt + K64, lb10); gload16(gb + kt + K64 + 32, lb11);
    __syncthreads();
#pragma unroll
    for (int h = 0; h < 2; ++h) {
      bf16x8 a[4], b[4];
#pragma unroll
      for (int i = 0; i < 4; ++i) {
        a[i] = *(const bf16x8*)&As[h * 4096 + (wr + i * 16 + ll) * 32 + lg * 8];
        b[i] = *(const bf16x8*)&Bs[h * 4096 + (wc + i * 16 + ll) * 32 + lg * 8];
      }
#pragma unroll
      for (int mi = 0; mi < 4; ++mi)
#pragma unroll
        for (int ni = 0; ni < 4; ++ni)
          acc[mi][ni] = mfma16(a[mi], b[ni], acc[mi][ni]);
    }
    __syncthreads();
  }
#pragma unroll
  for (int mi = 0; mi < 4; ++mi) {
#pragma unroll
    for (int r = 0; r < 4; ++r) {
      const int row = m0 + wr + mi * 16 + lg * 4 + r;
      float* crow = C + (size_t)row * N + n0 + wc;
#pragma unroll
      for (int ni = 0; ni < 4; ++ni)
        crow[ni * 16 + ll] = acc[mi][ni][r] + bias[n0 + wc + ni * 16 + ll];
    }
  }
}

// ---------------- flash attention v11: 256 q-rows per staged chunk ----------------
// 4 waves x 64 q (two 32-row halves per wave), 256-row q-tiles. Staging
// geometry + per-half compute = v5.1 VERBATIM. Halves independent -> MFMA/VALU
// cross-half overlap; staging bytes per q-row HALVED (the v5-vs-v6-identified
// controlling variable). Balance via R13's proven KV-split: tiles t>=3 split
// into two <=16-chunk segments (13 segments/bh, longest first); split segments
// emit fp32 partials + (m,l), attn_merge reconciles rows 768..2047.
#define ATTN_HALF(QF, MROW, LP, OA, OB, QGX, GATE)                              \
  {                                                                             \
    f32x16 s0 = {}, s1 = {};                                                    \
    __builtin_amdgcn_s_setprio(1);                                              \
    _Pragma("unroll")                                                           \
    for (int mi = 0; mi < 4; ++mi) {                                            \
      const int cb = mi * 32 + hi * 16;                                         \
      const bf16x8 k0 = *(const bf16x8*)(kvlds + ((ql * 128 + cb) ^ swz));      \
      const bf16x8 k1 = *(const bf16x8*)(kvlds + (((32 + ql) * 128 + cb) ^ swz));\
      s0 = mfma32(k0, QF[mi], s0);                                              \
      s1 = mfma32(k1, QF[mi], s1);                                              \
    }                                                                           \
    __builtin_amdgcn_s_setprio(0);                                              \
    if (kb + 63 > (GATE)) {                                                     \
      _Pragma("unroll")                                                         \
      for (int r = 0; r < 16; ++r) {                                            \
        const int kvo = (r & 3) + 8 * (r >> 2) + 4 * hi;                        \
        if (kb + kvo > (QGX)) s0[r] = -1e30f;                                   \
        if (kb + 32 + kvo > (QGX)) s1[r] = -1e30f;                              \
      }                                                                         \
    }                                                                           \
    float mx = s0[0];                                                           \
    _Pragma("unroll")                                                           \
    for (int r = 1; r < 16; ++r) mx = fmaxf(mx, s0[r]);                         \
    _Pragma("unroll")                                                           \
    for (int r = 0; r < 16; ++r) mx = fmaxf(mx, s1[r]);                         \
    mx = fmaxf(mx, __shfl_xor(mx, 32));                                         \
    if (!__all(mx <= MROW + 8.f)) {                                             \
      const float mn = fmaxf(MROW, mx);                                         \
      const float esc = __expf(MROW - mn);                                      \
      MROW = mn;                                                                \
      LP *= esc;                                                                \
      _Pragma("unroll")                                                         \
      for (int r = 0; r < 16; ++r) { OA[r] *= esc; OB[r] *= esc; }              \
    }                                                                           \
    float p0[16], p1[16];                                                       \
    _Pragma("unroll")                                                           \
    for (int r = 0; r < 16; ++r) {                                              \
      p0[r] = __expf(s0[r] - MROW);                                             \
      p1[r] = __expf(s1[r] - MROW);                                             \
      LP += p0[r] + p1[r];                                                      \
    }                                                                           \
    bf16x8 pb[4];                                                               \
    _Pragma("unroll")                                                           \
    for (int s = 0; s < 2; ++s) {                                               \
      const float* ps = s ? p1 : p0;                                            \
      _Pragma("unroll")                                                         \
      for (int j = 0; j < 2; ++j) {                                             \
        const unsigned X0 = pack2(ps[j * 8 + 0], ps[j * 8 + 1]);                \
        const unsigned X1 = pack2(ps[j * 8 + 2], ps[j * 8 + 3]);                \
        const unsigned Y0 = pack2(ps[j * 8 + 4], ps[j * 8 + 5]);                \
        const unsigned Y1 = pack2(ps[j * 8 + 6], ps[j * 8 + 7]);                \
        const unsigned sX0 = (unsigned)__shfl_xor((int)X0, 32);                 \
        const unsigned sX1 = (unsigned)__shfl_xor((int)X1, 32);                 \
        const unsigned sY0 = (unsigned)__shfl_xor((int)Y0, 32);                 \
        const unsigned sY1 = (unsigned)__shfl_xor((int)Y1, 32);                 \
        union { unsigned u[4]; bf16x8 v; } t;                                   \
        t.u[0] = hi ? sY0 : X0;                                                 \
        t.u[1] = hi ? sY1 : X1;                                                 \
        t.u[2] = hi ? Y0 : sX0;                                                 \
        t.u[3] = hi ? Y1 : sX1;                                                 \
        pb[s * 2 + j] = t.v;                                                    \
      }                                                                         \
    }                                                                           \
    __builtin_amdgcn_s_setprio(1);                                              \
    _Pragma("unroll")                                                           \
    for (int jj = 0; jj < 4; ++jj) {                                            \
      const int cb = jj * 32 + hi * 16;                                         \
      const bf16x8 va = *(const bf16x8*)(kvlds + 8192 + ((ql * 128 + cb) ^ swz));\
      const bf16x8 vb = *(const bf16x8*)(kvlds + 8192 + (((32 + ql) * 128 + cb) ^ swz));\
      OA = mfma32(va, pb[jj], OA);                                              \
      OB = mfma32(vb, pb[jj], OB);                                              \
    }                                                                           \
    __builtin_amdgcn_s_setprio(0);                                              \
  }

__global__ __launch_bounds__(256, 1)
void attn_k(const u16* __restrict__ qr, const u16* __restrict__ kr,
            const u16* __restrict__ vtc, u16* __restrict__ aout,
            float* __restrict__ pO, float* __restrict__ pML) {
  __shared__ __align__(16) char kvlds[16384];
  // segment tables: 13 segments/bh, ordered longest-first
  const signed char TT[13] = {7,7,6,6,5,5,2,4,4,3,3,1,0};
  const signed char HH[13] = {0,1,0,1,0,1,0,0,1,0,1,0,0};
  const signed char SP[13] = {1,1,1,1,1,1,0,1,1,1,1,0,0};
  const int bi = (int)blockIdx.x;
  const int bh = bi & 31;
  const int sidx = bi >> 5;                       // 0..12
  const int t = TT[sidx], half = HH[sidx];
  const bool split = SP[sidx];
  const int hlen = 2 * (t + 1);
  const int ch0 = split ? (half ? hlen : 0) : 0;
  const int ch1 = split ? (half ? 2 * hlen : hlen) : (4 * (t + 1));
  const int tid = threadIdx.x;
  const int w = tid >> 6, l = tid & 63, hi = l >> 5, ql = l & 31;
  const u16* Q  = qr + (size_t)bh * (2048 * 64);
  const u16* Kp = kr + (size_t)bh * (2048 * 64);
  const int q0w = (t << 8) + (w << 6);            // wave covers rows q0w..q0w+63
  const int qgA = q0w + ql;
  const int qgB = q0w + 32 + ql;
  bf16x8 qfA[4], qfB[4];
#pragma unroll
  for (int mi = 0; mi < 4; ++mi) {
    qfA[mi] = *(const bf16x8*)&Q[(size_t)qgA * 64 + mi * 16 + hi * 8];
    qfB[mi] = *(const bf16x8*)&Q[(size_t)qgB * 64 + mi * 16 + hi * 8];
  }
  const int sr = tid >> 2, sc = (tid & 3) * 32;
  const int wo0 = (sr * 128 + sc) ^ ((sr & 7) << 4);
  const int wo1 = (sr * 128 + sc + 16) ^ ((sr & 7) << 4);
  const char* kga = (const char*)(Kp + (size_t)sr * 64) + sc;
  const char* vga = (const char*)(vtc + (size_t)bh * 32 * 4096) + sr * 128 + sc;
  const int swz = (ql & 7) << 4;
  f32x16 oaA = {}, obA = {}, oaB = {}, obB = {};
  float mrowA = -1e30f, lpA = 0.f, mrowB = -1e30f, lpB = 0.f;
  uint4 sk0 = *(const uint4*)(kga + (size_t)ch0 * 8192);
  uint4 sk1 = *(const uint4*)(kga + (size_t)ch0 * 8192 + 16);
  uint4 sv0 = *(const uint4*)(vga + (size_t)ch0 * 8192);
  uint4 sv1 = *(const uint4*)(vga + (size_t)ch0 * 8192 + 16);
  for (int ch = ch0; ch < ch1; ++ch) {
    asm volatile("s_waitcnt vmcnt(0)" ::: "memory");
    asm volatile("s_barrier" ::: "memory");
    *(uint4*)(kvlds + wo0) = sk0;
    *(uint4*)(kvlds + wo1) = sk1;
    *(uint4*)(kvlds + 8192 + wo0) = sv0;
    *(uint4*)(kvlds + 8192 + wo1) = sv1;
    if (ch + 1 < ch1) {
      const size_t kof = (size_t)(ch + 1) * 8192;
      sk0 = *(const uint4*)(kga + kof); sk1 = *(const uint4*)(kga + kof + 16);
      sv0 = *(const uint4*)(vga + kof); sv1 = *(const uint4*)(vga + kof + 16);
    }
    asm volatile("s_waitcnt lgkmcnt(0)" ::: "memory");
    asm volatile("s_barrier" ::: "memory");
    const int kb = ch << 6;
    if (kb > q0w + 63) continue;                 // whole wave fully masked
    if (kb <= q0w + 31)                          // half A live
      ATTN_HALF(qfA, mrowA, lpA, oaA, obA, qgA, q0w)
    ATTN_HALF(qfB, mrowB, lpB, oaB, obB, qgB, q0w + 32)
  }
  lpA += __shfl_xor(lpA, 32);
  lpB += __shfl_xor(lpB, 32);
  const int hcol = (bh & 15) << 6;
  if (!split) {
    const float invA = 1.0f / lpA, invB = 1.0f / lpB;
    const int tokA = ((bh >> 4) << 11) + qgA;
    const int tokB = ((bh >> 4) << 11) + qgB;
    unsigned* orowA = (unsigned*)(aout + (size_t)tokA * 1024 + hcol);
    unsigned* orowB = (unsigned*)(aout + (size_t)tokB * 1024 + hcol);
#pragma unroll
    for (int r = 0; r < 16; r += 2) {
      const int d0 = (r & 3) + 8 * (r >> 2) + 4 * hi;
      orowA[d0 >> 1]        = pack2(oaA[r] * invA, oaA[r + 1] * invA);
      orowA[(32 + d0) >> 1] = pack2(obA[r] * invA, obA[r + 1] * invA);
      orowB[d0 >> 1]        = pack2(oaB[r] * invB, oaB[r + 1] * invB);
      orowB[(32 + d0) >> 1] = pack2(obB[r] * invB, obB[r + 1] * invB);
    }
  } else {
    // rows 768..2047 -> partials. ridx = bh*1280 + (qg-768)
    const int ridxA = bh * 1280 + (qgA - 768);
    const int ridxB = bh * 1280 + (qgB - 768);
    float* prowA = pO + ((size_t)ridxA * 2 + half) * 64;
    float* prowB = pO + ((size_t)ridxB * 2 + half) * 64;
#pragma unroll
    for (int r = 0; r < 16; r += 2) {
      const int d0 = (r & 3) + 8 * (r >> 2) + 4 * hi;
      *(float2*)&prowA[d0]      = make_float2(oaA[r], oaA[r + 1]);
      *(float2*)&prowA[32 + d0] = make_float2(obA[r], obA[r + 1]);
      *(float2*)&prowB[d0]      = make_float2(oaB[r], oaB[r + 1]);
      *(float2*)&prowB[32 + d0] = make_float2(obB[r], obB[r + 1]);
    }
    if (hi == 0) {
      pML[((size_t)ridxA * 2 + half) * 2 + 0] = mrowA;
      pML[((size_t)ridxA * 2 + half) * 2 + 1] = lpA;
      pML[((size_t)ridxB * 2 + half) * 2 + 0] = mrowB;
      pML[((size_t)ridxB * 2 + half) * 2 + 1] = lpB;
    }
  }
}

// ---------------- merge the two KV-split partials (rows 768..2047) ----------------
__global__ void attn_merge(const float* __restrict__ pO, const float* __restrict__ pML,
                           u16* __restrict__ aout) {
  const int idx = (int)blockIdx.x * 256 + threadIdx.x;  // 32*1280*64 lanes
  const int d = idx & 63;
  const int rr = idx >> 6;                              // 0..40959
  const float mA = pML[rr * 4 + 0], lA = pML[rr * 4 + 1];
  const float mB = pML[rr * 4 + 2], lB = pML[rr * 4 + 3];
  const float M = fmaxf(mA, mB);
  const float eA = __expf(mA - M), eB = __expf(mB - M);
  const float num = pO[((size_t)rr * 2 + 0) * 64 + d] * eA
                  + pO[((size_t)rr * 2 + 1) * 64 + d] * eB;
  const float den = lA * eA + lB * eB;
  const int bh = rr / 1280, row = (rr % 1280) + 768;
  const int tok = ((bh >> 4) << 11) + row;
  const int hcol = (bh & 15) << 6;
  aout[(size_t)tok * 1024 + hcol + d] = f2bf(num / den);
}

extern "C" void kernel_launch(void* const* d_in, const int* in_sizes, int n_in,
                              void* d_out, int out_size, void* d_ws, size_t ws_size,
                              hipStream_t stream) {
  const float* x    = (const float*)d_in[0];
  const float* fc   = (const float*)d_in[2];
  const float* fs   = (const float*)d_in[3];
  const float* Wqkv = (const float*)d_in[4];
  const float* bqkv = (const float*)d_in[5];
  const float* Wo   = (const float*)d_in[6];
  const float* bo   = (const float*)d_in[7];
  float* out = (float*)d_out;

  size_t off = 0;
  auto alloc = [&](size_t bytes) {
    void* p = (char*)d_ws + off;
    off += (bytes + 255) & ~(size_t)255;
    return p;
  };
  u16*   xb   = (u16*)  alloc(4096ull * 1024 * 2);
  u16*   wqt  = (u16*)  alloc(3072ull * 1024 * 2);
  u16*   wot  = (u16*)  alloc(1024ull * 1024 * 2);
  u16*   qr_  = (u16*)  alloc(32ull * 2048 * 64 * 2);
  u16*   kr_  = (u16*)  alloc(32ull * 2048 * 64 * 2);
  u16*   vtc_ = (u16*)  alloc(32ull * 32 * 4096 * 2);
  u16*   ao_  = (u16*)  alloc(4096ull * 1024 * 2);
  float* pO_  = (float*)alloc(32ull * 1280 * 2 * 64 * 4);
  float* pML_ = (float*)alloc(32ull * 1280 * 2 * 2 * 4);

  cast_bf16_kernel<<<2048, 256, 0, stream>>>(x, xb, 4096 * 1024);
  transpose_cast_k<<<dim3(48, 16), 256, 0, stream>>>(Wqkv, wqt, 1024, 3072);
  transpose_cast_k<<<dim3(16, 16), 256, 0, stream>>>(Wo, wot, 1024, 1024);
  gemm_qkv<<<dim3(32 * 24), 256, 0, stream>>>(xb, wqt, bqkv, fc, fs, qr_, kr_, vtc_);
  attn_k<<<dim3(13 * 32), 256, 0, stream>>>(qr_, kr_, vtc_, ao_, pO_, pML_);
  attn_merge<<<dim3(10240), 256, 0, stream>>>(pO_, pML_, ao_);
  gemm_bt<<<dim3(32 * 8), 256, 0, stream>>>(ao_, wot, bo, out, 4096, 1024, 1024);
}

// Round 17
// 125.972 us; speedup vs baseline: 1.2717x; 1.2717x over previous
//
#include <hip/hip_runtime.h>
#include <hip/hip_bf16.h>
#include <stdint.h>

typedef unsigned short u16;
typedef __attribute__((ext_vector_type(8))) __bf16 bf16x8;
typedef __attribute__((ext_vector_type(4))) float f32x4;
typedef __attribute__((ext_vector_type(16))) float f32x16;
typedef __attribute__((ext_vector_type(8))) u16 u16x8;

__device__ __forceinline__ u16 f2bf(float f) {
  union { float f; unsigned int u; } v; v.f = f;
  unsigned int r = v.u + 0x7fffu + ((v.u >> 16) & 1u);
  return (u16)(r >> 16);
}
__device__ __forceinline__ unsigned pack2(float lo, float hi) {
  return (unsigned)f2bf(lo) | ((unsigned)f2bf(hi) << 16);
}

__device__ __forceinline__ f32x4 mfma16(bf16x8 a, bf16x8 b, f32x4 c) {
  return __builtin_amdgcn_mfma_f32_16x16x32_bf16(a, b, c, 0, 0, 0);
}
__device__ __forceinline__ f32x16 mfma32(bf16x8 a, bf16x8 b, f32x16 c) {
  return __builtin_amdgcn_mfma_f32_32x32x16_bf16(a, b, c, 0, 0, 0);
}

__device__ __forceinline__ void gload16(const void* g, void* l) {
  __builtin_amdgcn_global_load_lds((const __attribute__((address_space(1))) void*)g,
                                   (__attribute__((address_space(3))) void*)l,
                                   16, 0, 0);
}

// ---------------- elementwise cast fp32 -> bf16 ----------------
__global__ void cast_bf16_kernel(const float* __restrict__ in, u16* __restrict__ out, int n) {
  int i = (blockIdx.x * 256 + threadIdx.x) * 8;
  if (i >= n) return;
  const float4* p = (const float4*)(in + i);
  float4 a = p[0], b = p[1];
  u16x8 o;
  o[0] = f2bf(a.x); o[1] = f2bf(a.y); o[2] = f2bf(a.z); o[3] = f2bf(a.w);
  o[4] = f2bf(b.x); o[5] = f2bf(b.y); o[6] = f2bf(b.z); o[7] = f2bf(b.w);
  *(u16x8*)(out + i) = o;
}

// ---------------- transpose + cast: in[R][C] fp32 -> out[C][R] bf16 ----------------
__global__ void transpose_cast_k(const float* __restrict__ in, u16* __restrict__ out,
                                 int R, int Ccols) {
  __shared__ float tile[64][65];
  const int c0 = (int)blockIdx.x << 6, r0 = (int)blockIdx.y << 6;
  const int tx = threadIdx.x & 63, ty = threadIdx.x >> 6;
#pragma unroll
  for (int i = ty; i < 64; i += 4)
    tile[i][tx] = in[(size_t)(r0 + i) * Ccols + c0 + tx];
  __syncthreads();
#pragma unroll
  for (int i = ty; i < 64; i += 4)
    out[(size_t)(c0 + i) * R + r0 + tx] = f2bf(tile[tx][i]);
}

// ---------------- QKV GEMM, BK=64, fused bias+RoPE+head-split epilogue ----------------
// V section writes chunked-transposed vtc[bh][ch][64 d][64 s] directly (R14).
// XCD-aware block swizzle (T1): grid 768 = 8 XCDs x 96 contiguous blocks ->
// each XCD keeps 4 m-bands' A-panels L2-resident.
__global__ __launch_bounds__(256, 3)
void gemm_qkv(const u16* __restrict__ A, const u16* __restrict__ Bt,
              const float* __restrict__ bias,
              const float* __restrict__ fc, const float* __restrict__ fs,
              u16* __restrict__ qr, u16* __restrict__ kr, u16* __restrict__ vtc) {
  const int K = 1024;
  __shared__ __align__(16) u16 smem[128 * 136];
  u16* const As = smem;
  u16* const Bs = smem + 8192;
  const int bid = (int)blockIdx.x;
  const int swb = (bid & 7) * 96 + (bid >> 3);   // bijective XCD swizzle (768 % 8 == 0)
  const int m0 = (swb / 24) << 7;
  const int n0 = (swb % 24) << 7;
  const int tid = threadIdx.x;
  const int l = tid & 63, lg = l >> 4, ll = l & 15;
  const int w = tid >> 6;
  const int wr = (w >> 1) << 6, wc = (w & 1) << 6;
  const int srow = tid >> 2, scol = (tid & 3) << 3;
  const u16* ga = A + (size_t)(m0 + srow) * K + scol;
  const u16* gb = Bt + (size_t)(n0 + srow) * K + scol;
  const size_t K64 = (size_t)64 * K;
  u16* const la00 = &As[srow * 32 + scol];
  u16* const la01 = &As[4096 + srow * 32 + scol];
  u16* const la10 = &As[(srow + 64) * 32 + scol];
  u16* const la11 = &As[4096 + (srow + 64) * 32 + scol];
  u16* const lb00 = &Bs[srow * 32 + scol];
  u16* const lb01 = &Bs[4096 + srow * 32 + scol];
  u16* const lb10 = &Bs[(srow + 64) * 32 + scol];
  u16* const lb11 = &Bs[4096 + (srow + 64) * 32 + scol];
  f32x4 acc[4][4] = {};
  for (int kt = 0; kt < K; kt += 64) {
    gload16(ga + kt, la00);       gload16(ga + kt + 32, la01);
    gload16(ga + kt + K64, la10); gload16(ga + kt + K64 + 32, la11);
    gload16(gb + kt, lb00);       gload16(gb + kt + 32, lb01);
    gload16(gb + kt + K64, lb10); gload16(gb + kt + K64 + 32, lb11);
    __syncthreads();
#pragma unroll
    for (int h = 0; h < 2; ++h) {
      bf16x8 a[4], b[4];
#pragma unroll
      for (int i = 0; i < 4; ++i) {
        a[i] = *(const bf16x8*)&As[h * 4096 + (wr + i * 16 + ll) * 32 + lg * 8];
        b[i] = *(const bf16x8*)&Bs[h * 4096 + (wc + i * 16 + ll) * 32 + lg * 8];
      }
#pragma unroll
      for (int mi = 0; mi < 4; ++mi)
#pragma unroll
        for (int ni = 0; ni < 4; ++ni)
          acc[mi][ni] = mfma16(a[mi], b[ni], acc[mi][ni]);
    }
    __syncthreads();
  }
  // ---- stage 1: bias (+rope for Q/K) -> LDS tile ----
  const int sec = n0 >> 10;                       // 0=Q, 1=K, 2=V
  const int h0 = (n0 & 1023) >> 6;
#pragma unroll
  for (int ni = 0; ni < 4; ++ni) {
    const int cc = wc + ni * 16 + ll;
    const int n = n0 + cc;
    const int d = n & 63;
    const float bi_ = bias[n];
    const int i2 = d >> 1;
    const bool odd = d & 1;
#pragma unroll
    for (int mi = 0; mi < 4; ++mi) {
#pragma unroll
      for (int r = 0; r < 4; ++r) {
        const int rr = wr + mi * 16 + lg * 4 + r;
        const int s = (m0 + rr) & 2047;
        float v = acc[mi][ni][r] + bi_;
        if (sec < 2) {
          const float c = fc[s * 32 + i2], sn = fs[s * 32 + i2];
          const float p = __shfl_xor(v, 1);
          v = odd ? (p * sn + v * c) : (v * c - p * sn);
          if (sec == 0) v *= 0.125f;
          smem[rr * 136 + cc] = f2bf(v);
        } else {
          smem[cc * 136 + rr] = f2bf(v);        // transposed for vtc
        }
      }
    }
  }
  __syncthreads();
  // ---- stage 2: coalesced uint4 stores ----
  if (sec < 2) {
    u16* const dst = (sec == 0) ? qr : kr;
#pragma unroll
    for (int it = 0; it < 8; ++it) {
      const int c = it * 256 + tid;
      const int j = c & 7, hh = (c >> 3) & 1, rr = c >> 4;
      const int row = m0 + rr;
      const int bb = row >> 11, ss = row & 2047;
      const uint4 val = *(const uint4*)&smem[rr * 136 + hh * 64 + j * 8];
      *(uint4*)&dst[((size_t)(((bb << 4) + h0 + hh) << 11) + ss) * 64 + j * 8] = val;
    }
  } else {
    const int b16 = (m0 >> 11) << 4;
    const int chbase = (m0 & 2047) >> 6;
#pragma unroll
    for (int it = 0; it < 8; ++it) {
      const int c = it * 256 + tid;
      const int j2 = c & 7;
      const int rr2 = c >> 3;
      const int d = rr2 & 63, hh = (rr2 >> 6) & 1, chk = rr2 >> 7;
      const uint4 val = *(const uint4*)&smem[(hh * 64 + d) * 136 + chk * 64 + j2 * 8];
      *(uint4*)&vtc[(((size_t)(b16 + h0 + hh)) * 32 + chbase + chk) * 4096 + d * 64 + j2 * 8] = val;
    }
  }
}

// ---------------- GEMM (O-proj): BK=64, fp32 out, XCD swizzle ----------------
__global__ __launch_bounds__(256, 2)
void gemm_bt(const u16* __restrict__ A, const u16* __restrict__ Bt,
             const float* __restrict__ bias, float* __restrict__ C,
             int M, int N, int K) {
  __shared__ __align__(16) u16 As[2 * 128 * 32];
  __shared__ __align__(16) u16 Bs[2 * 128 * 32];
  const int nb = N >> 7;
  const int nwg = (M >> 7) * nb;
  const int bid = (int)blockIdx.x;
  const int cpx = nwg >> 3;                       // grid % 8 == 0 for all uses
  const int swb = (bid & 7) * cpx + (bid >> 3);
  const int m0 = (swb / nb) << 7;
  const int n0 = (swb % nb) << 7;
  const int tid = threadIdx.x;
  const int l = tid & 63, lg = l >> 4, ll = l & 15;
  const int w = tid >> 6;
  const int wr = (w >> 1) << 6, wc = (w & 1) << 6;
  const int srow = tid >> 2, scol = (tid & 3) << 3;
  const u16* ga = A + (size_t)(m0 + srow) * K + scol;
  const u16* gb = Bt + (size_t)(n0 + srow) * K + scol;
  const size_t K64 = (size_t)64 * K;
  u16* const la00 = &As[srow * 32 + scol];
  u16* const la01 = &As[4096 + srow * 32 + scol];
  u16* const la10 = &As[(srow + 64) * 32 + scol];
  u16* const la11 = &As[4096 + (srow + 64) * 32 + scol];
  u16* const lb00 = &Bs[srow * 32 + scol];
  u16* const lb01 = &Bs[4096 + srow * 32 + scol];
  u16* const lb10 = &Bs[(srow + 64) * 32 + scol];
  u16* const lb11 = &Bs[4096 + (srow + 64) * 32 + scol];
  f32x4 acc[4][4] = {};
  for (int kt = 0; kt < K; kt += 64) {
    gload16(ga + kt, la00);       gload16(ga + kt + 32, la01);
    gload16(ga + kt + K64, la10); gload16(ga + kt + K64 + 32, la11);
    gload16(gb + kt, lb00);       gload16(gb + kt + 32, lb01);
    gload16(gb + kt + K64, lb10); gload16(gb + kt + K64 + 32, lb11);
    __syncthreads();
#pragma unroll
    for (int h = 0; h < 2; ++h) {
      bf16x8 a[4], b[4];
#pragma unroll
      for (int i = 0; i < 4; ++i) {
        a[i] = *(const bf16x8*)&As[h * 4096 + (wr + i * 16 + ll) * 32 + lg * 8];
        b[i] = *(const bf16x8*)&Bs[h * 4096 + (wc + i * 16 + ll) * 32 + lg * 8];
      }
#pragma unroll
      for (int mi = 0; mi < 4; ++mi)
#pragma unroll
        for (int ni = 0; ni < 4; ++ni)
          acc[mi][ni] = mfma16(a[mi], b[ni], acc[mi][ni]);
    }
    __syncthreads();
  }
#pragma unroll
  for (int mi = 0; mi < 4; ++mi) {
#pragma unroll
    for (int r = 0; r < 4; ++r) {
      const int row = m0 + wr + mi * 16 + lg * 4 + r;
      float* crow = C + (size_t)row * N + n0 + wc;
#pragma unroll
      for (int ni = 0; ni < 4; ++ni)
        crow[ni * 16 + ll] = acc[mi][ni][r] + bias[n0 + wc + ni * 16 + ll];
    }
  }
}

// ---------------- flash attention v5.1 (R11/R14 verbatim, best known) ----------------
__global__ __launch_bounds__(256, 2)
void attn_k(const u16* __restrict__ qr, const u16* __restrict__ kr,
            const u16* __restrict__ vtc, u16* __restrict__ aout) {
  __shared__ __align__(16) char kvlds[16384];     // [0:8K) K tile, [8K:16K) V^T tile
  const int bi = (int)blockIdx.x;
  const int bh = bi & 31;
  const int qt = (bi < 256) ? (15 - (bi >> 5)) : ((bi - 256) >> 5);
  const int tid = threadIdx.x;
  const int w = tid >> 6, l = tid & 63, hi = l >> 5, ql = l & 31;
  const u16* Q  = qr + (size_t)bh * (2048 * 64);
  const u16* Kp = kr + (size_t)bh * (2048 * 64);
  const int q0w = (qt << 7) + (w << 5);
  const int qg = q0w + ql;
  bf16x8 qf[4];
#pragma unroll
  for (int mi = 0; mi < 4; ++mi)
    qf[mi] = *(const bf16x8*)&Q[(size_t)qg * 64 + mi * 16 + hi * 8];
  const int sr = tid >> 2, sc = (tid & 3) * 32;
  const int wo0 = (sr * 128 + sc) ^ ((sr & 7) << 4);
  const int wo1 = (sr * 128 + sc + 16) ^ ((sr & 7) << 4);
  const char* kga = (const char*)(Kp + (size_t)sr * 64) + sc;                    // + ch*8192
  const char* vga = (const char*)(vtc + (size_t)bh * 32 * 4096) + sr * 128 + sc; // + ch*8192
  const int swz = (ql & 7) << 4;
  f32x16 oa = {}, ob = {};
  float mrow = -1e30f, lp = 0.f;
  const int nch = 2 * qt + 2;
  uint4 sk0 = *(const uint4*)(kga), sk1 = *(const uint4*)(kga + 16);
  uint4 sv0 = *(const uint4*)(vga), sv1 = *(const uint4*)(vga + 16);
  for (int ch = 0; ch < nch; ++ch) {
    asm volatile("s_waitcnt vmcnt(0)" ::: "memory");
    asm volatile("s_barrier" ::: "memory");
    *(uint4*)(kvlds + wo0) = sk0;
    *(uint4*)(kvlds + wo1) = sk1;
    *(uint4*)(kvlds + 8192 + wo0) = sv0;
    *(uint4*)(kvlds + 8192 + wo1) = sv1;
    if (ch + 1 < nch) {
      const size_t kof = (size_t)(ch + 1) * 8192;
      sk0 = *(const uint4*)(kga + kof); sk1 = *(const uint4*)(kga + kof + 16);
      sv0 = *(const uint4*)(vga + kof); sv1 = *(const uint4*)(vga + kof + 16);
    }
    asm volatile("s_waitcnt lgkmcnt(0)" ::: "memory");
    asm volatile("s_barrier" ::: "memory");
    const int kb = ch << 6;
    if (kb > q0w + 31) continue;
    f32x16 s0 = {}, s1 = {};
#pragma unroll
    for (int mi = 0; mi < 4; ++mi) {
      const int cb = mi * 32 + hi * 16;
      const bf16x8 k0 = *(const bf16x8*)(kvlds + ((ql * 128 + cb) ^ swz));
      const bf16x8 k1 = *(const bf16x8*)(kvlds + (((32 + ql) * 128 + cb) ^ swz));
      s0 = mfma32(k0, qf[mi], s0);
      s1 = mfma32(k1, qf[mi], s1);
    }
    if (kb + 63 > q0w) {
#pragma unroll
      for (int r = 0; r < 16; ++r) {
        const int kvo = (r & 3) + 8 * (r >> 2) + 4 * hi;
        if (kb + kvo > qg) s0[r] = -1e30f;
        if (kb + 32 + kvo > qg) s1[r] = -1e30f;
      }
    }
    float mx = s0[0];
#pragma unroll
    for (int r = 1; r < 16; ++r) mx = fmaxf(mx, s0[r]);
#pragma unroll
    for (int r = 0; r < 16; ++r) mx = fmaxf(mx, s1[r]);
    mx = fmaxf(mx, __shfl_xor(mx, 32));
    if (!__all(mx <= mrow + 8.f)) {
      const float mn = fmaxf(mrow, mx);
      const float esc = __expf(mrow - mn);
      mrow = mn;
      lp *= esc;
#pragma unroll
      for (int r = 0; r < 16; ++r) { oa[r] *= esc; ob[r] *= esc; }
    }
    float p0[16], p1[16];
#pragma unroll
    for (int r = 0; r < 16; ++r) {
      p0[r] = __expf(s0[r] - mrow);
      p1[r] = __expf(s1[r] - mrow);
      lp += p0[r] + p1[r];
    }
    bf16x8 pb[4];
#pragma unroll
    for (int s = 0; s < 2; ++s) {
      const float* ps = s ? p1 : p0;
#pragma unroll
      for (int j = 0; j < 2; ++j) {
        const unsigned X0 = pack2(ps[j * 8 + 0], ps[j * 8 + 1]);
        const unsigned X1 = pack2(ps[j * 8 + 2], ps[j * 8 + 3]);
        const unsigned Y0 = pack2(ps[j * 8 + 4], ps[j * 8 + 5]);
        const unsigned Y1 = pack2(ps[j * 8 + 6], ps[j * 8 + 7]);
        const unsigned sX0 = (unsigned)__shfl_xor((int)X0, 32);
        const unsigned sX1 = (unsigned)__shfl_xor((int)X1, 32);
        const unsigned sY0 = (unsigned)__shfl_xor((int)Y0, 32);
        const unsigned sY1 = (unsigned)__shfl_xor((int)Y1, 32);
        union { unsigned u[4]; bf16x8 v; } t;
        t.u[0] = hi ? sY0 : X0;
        t.u[1] = hi ? sY1 : X1;
        t.u[2] = hi ? Y0 : sX0;
        t.u[3] = hi ? Y1 : sX1;
        pb[s * 2 + j] = t.v;
      }
    }
#pragma unroll
    for (int jj = 0; jj < 4; ++jj) {
      const int cb = jj * 32 + hi * 16;
      const bf16x8 va = *(const bf16x8*)(kvlds + 8192 + ((ql * 128 + cb) ^ swz));
      const bf16x8 vb = *(const bf16x8*)(kvlds + 8192 + (((32 + ql) * 128 + cb) ^ swz));
      oa = mfma32(va, pb[jj], oa);
      ob = mfma32(vb, pb[jj], ob);
    }
  }
  lp += __shfl_xor(lp, 32);
  const float inv = 1.0f / lp;
  const int hcol = (bh & 15) << 6;
  const int tok = ((bh >> 4) << 11) + qg;
  unsigned* orow = (unsigned*)(aout + (size_t)tok * 1024 + hcol);
#pragma unroll
  for (int r = 0; r < 16; r += 2) {
    const int d0 = (r & 3) + 8 * (r >> 2) + 4 * hi;
    orow[d0 >> 1]        = pack2(oa[r] * inv, oa[r + 1] * inv);
    orow[(32 + d0) >> 1] = pack2(ob[r] * inv, ob[r + 1] * inv);
  }
}

extern "C" void kernel_launch(void* const* d_in, const int* in_sizes, int n_in,
                              void* d_out, int out_size, void* d_ws, size_t ws_size,
                              hipStream_t stream) {
  const float* x    = (const float*)d_in[0];
  const float* fc   = (const float*)d_in[2];
  const float* fs   = (const float*)d_in[3];
  const float* Wqkv = (const float*)d_in[4];
  const float* bqkv = (const float*)d_in[5];
  const float* Wo   = (const float*)d_in[6];
  const float* bo   = (const float*)d_in[7];
  float* out = (float*)d_out;

  size_t off = 0;
  auto alloc = [&](size_t bytes) {
    void* p = (char*)d_ws + off;
    off += (bytes + 255) & ~(size_t)255;
    return p;
  };
  u16*   xb   = (u16*)  alloc(4096ull * 1024 * 2);   // x bf16
  u16*   wqt  = (u16*)  alloc(3072ull * 1024 * 2);   // W_qkv^T bf16
  u16*   wot  = (u16*)  alloc(1024ull * 1024 * 2);   // W_o^T bf16
  u16*   qr_  = (u16*)  alloc(32ull * 2048 * 64 * 2);// q roped, head-major
  u16*   kr_  = (u16*)  alloc(32ull * 2048 * 64 * 2);// k roped, head-major
  u16*   vtc_ = (u16*)  alloc(32ull * 32 * 4096 * 2);// v^T chunked [bh][ch][d][64]
  u16*   ao_  = (u16*)  alloc(4096ull * 1024 * 2);   // attention out bf16

  cast_bf16_kernel<<<2048, 256, 0, stream>>>(x, xb, 4096 * 1024);
  transpose_cast_k<<<dim3(48, 16), 256, 0, stream>>>(Wqkv, wqt, 1024, 3072);
  transpose_cast_k<<<dim3(16, 16), 256, 0, stream>>>(Wo, wot, 1024, 1024);
  gemm_qkv<<<dim3(32 * 24), 256, 0, stream>>>(xb, wqt, bqkv, fc, fs, qr_, kr_, vtc_);
  attn_k<<<dim3(512), 256, 0, stream>>>(qr_, kr_, vtc_, ao_);
  gemm_bt<<<dim3(32 * 8), 256, 0, stream>>>(ao_, wot, bo, out, 4096, 1024, 1024);
}

// Round 18
// 118.368 us; speedup vs baseline: 1.3534x; 1.0642x over previous
//
#include <hip/hip_runtime.h>
#include <hip/hip_bf16.h>
#include <stdint.h>

typedef unsigned short u16;
typedef __attribute__((ext_vector_type(8))) __bf16 bf16x8;
typedef __attribute__((ext_vector_type(4))) float f32x4;
typedef __attribute__((ext_vector_type(16))) float f32x16;
typedef __attribute__((ext_vector_type(8))) u16 u16x8;

__device__ __forceinline__ u16 f2bf(float f) {
  union { float f; unsigned int u; } v; v.f = f;
  unsigned int r = v.u + 0x7fffu + ((v.u >> 16) & 1u);
  return (u16)(r >> 16);
}
__device__ __forceinline__ unsigned pack2(float lo, float hi) {
  return (unsigned)f2bf(lo) | ((unsigned)f2bf(hi) << 16);
}

__device__ __forceinline__ f32x4 mfma16(bf16x8 a, bf16x8 b, f32x4 c) {
  return __builtin_amdgcn_mfma_f32_16x16x32_bf16(a, b, c, 0, 0, 0);
}
__device__ __forceinline__ f32x16 mfma32(bf16x8 a, bf16x8 b, f32x16 c) {
  return __builtin_amdgcn_mfma_f32_32x32x16_bf16(a, b, c, 0, 0, 0);
}

__device__ __forceinline__ void gload16(const void* g, void* l) {
  __builtin_amdgcn_global_load_lds((const __attribute__((address_space(1))) void*)g,
                                   (__attribute__((address_space(3))) void*)l,
                                   16, 0, 0);
}

// ---------------- fused prep: cast x + transpose-cast Wqkv + transpose-cast Wo ----------------
// blocks [0,2048): cast x fp32->bf16 (8 elems/thread)
// blocks [2048,2816): Wqkv [1024][3072] -> wqt [3072][1024] bf16  (48 x 16 tiles)
// blocks [2816,3072): Wo   [1024][1024] -> wot [1024][1024] bf16  (16 x 16 tiles)
// Merges 3 dispatches into 1: deletes 2 launch gaps; small transposes
// co-schedule with the cast instead of serializing after it.
__global__ __launch_bounds__(256)
void prep_kernel(const float* __restrict__ x, u16* __restrict__ xb,
                 const float* __restrict__ Wqkv, u16* __restrict__ wqt,
                 const float* __restrict__ Wo, u16* __restrict__ wot) {
  __shared__ float tile[64][65];
  const int bid = (int)blockIdx.x;
  if (bid < 2048) {
    const int i = (bid * 256 + (int)threadIdx.x) * 8;
    const float4* p = (const float4*)(x + i);
    float4 a = p[0], b = p[1];
    u16x8 o;
    o[0] = f2bf(a.x); o[1] = f2bf(a.y); o[2] = f2bf(a.z); o[3] = f2bf(a.w);
    o[4] = f2bf(b.x); o[5] = f2bf(b.y); o[6] = f2bf(b.z); o[7] = f2bf(b.w);
    *(u16x8*)(xb + i) = o;
    return;
  }
  const float* in;
  u16* out;
  int R, Ccols, c0, r0;
  if (bid < 2816) {
    const int t = bid - 2048;            // 48 x 16
    in = Wqkv; out = wqt; R = 1024; Ccols = 3072;
    c0 = (t % 48) << 6; r0 = (t / 48) << 6;
  } else {
    const int t = bid - 2816;            // 16 x 16
    in = Wo; out = wot; R = 1024; Ccols = 1024;
    c0 = (t % 16) << 6; r0 = (t / 16) << 6;
  }
  const int tx = threadIdx.x & 63, ty = threadIdx.x >> 6;
#pragma unroll
  for (int i = ty; i < 64; i += 4)
    tile[i][tx] = in[(size_t)(r0 + i) * Ccols + c0 + tx];
  __syncthreads();
#pragma unroll
  for (int i = ty; i < 64; i += 4)
    out[(size_t)(c0 + i) * R + r0 + tx] = f2bf(tile[tx][i]);
}

// ---------------- QKV GEMM, BK=64, fused bias+RoPE+head-split epilogue ----------------
// V section writes chunked-transposed vtc[bh][ch][64 d][64 s] directly (R14).
// XCD-aware block swizzle (T1): grid 768 = 8 XCDs x 96 contiguous blocks.
__global__ __launch_bounds__(256, 3)
void gemm_qkv(const u16* __restrict__ A, const u16* __restrict__ Bt,
              const float* __restrict__ bias,
              const float* __restrict__ fc, const float* __restrict__ fs,
              u16* __restrict__ qr, u16* __restrict__ kr, u16* __restrict__ vtc) {
  const int K = 1024;
  __shared__ __align__(16) u16 smem[128 * 136];
  u16* const As = smem;
  u16* const Bs = smem + 8192;
  const int bid = (int)blockIdx.x;
  const int swb = (bid & 7) * 96 + (bid >> 3);   // bijective XCD swizzle (768 % 8 == 0)
  const int m0 = (swb / 24) << 7;
  const int n0 = (swb % 24) << 7;
  const int tid = threadIdx.x;
  const int l = tid & 63, lg = l >> 4, ll = l & 15;
  const int w = tid >> 6;
  const int wr = (w >> 1) << 6, wc = (w & 1) << 6;
  const int srow = tid >> 2, scol = (tid & 3) << 3;
  const u16* ga = A + (size_t)(m0 + srow) * K + scol;
  const u16* gb = Bt + (size_t)(n0 + srow) * K + scol;
  const size_t K64 = (size_t)64 * K;
  u16* const la00 = &As[srow * 32 + scol];
  u16* const la01 = &As[4096 + srow * 32 + scol];
  u16* const la10 = &As[(srow + 64) * 32 + scol];
  u16* const la11 = &As[4096 + (srow + 64) * 32 + scol];
  u16* const lb00 = &Bs[srow * 32 + scol];
  u16* const lb01 = &Bs[4096 + srow * 32 + scol];
  u16* const lb10 = &Bs[(srow + 64) * 32 + scol];
  u16* const lb11 = &Bs[4096 + (srow + 64) * 32 + scol];
  f32x4 acc[4][4] = {};
  for (int kt = 0; kt < K; kt += 64) {
    gload16(ga + kt, la00);       gload16(ga + kt + 32, la01);
    gload16(ga + kt + K64, la10); gload16(ga + kt + K64 + 32, la11);
    gload16(gb + kt, lb00);       gload16(gb + kt + 32, lb01);
    gload16(gb + kt + K64, lb10); gload16(gb + kt + K64 + 32, lb11);
    __syncthreads();
#pragma unroll
    for (int h = 0; h < 2; ++h) {
      bf16x8 a[4], b[4];
#pragma unroll
      for (int i = 0; i < 4; ++i) {
        a[i] = *(const bf16x8*)&As[h * 4096 + (wr + i * 16 + ll) * 32 + lg * 8];
        b[i] = *(const bf16x8*)&Bs[h * 4096 + (wc + i * 16 + ll) * 32 + lg * 8];
      }
#pragma unroll
      for (int mi = 0; mi < 4; ++mi)
#pragma unroll
        for (int ni = 0; ni < 4; ++ni)
          acc[mi][ni] = mfma16(a[mi], b[ni], acc[mi][ni]);
    }
    __syncthreads();
  }
  // ---- stage 1: bias (+rope for Q/K) -> LDS tile ----
  const int sec = n0 >> 10;                       // 0=Q, 1=K, 2=V
  const int h0 = (n0 & 1023) >> 6;
#pragma unroll
  for (int ni = 0; ni < 4; ++ni) {
    const int cc = wc + ni * 16 + ll;
    const int n = n0 + cc;
    const int d = n & 63;
    const float bi_ = bias[n];
    const int i2 = d >> 1;
    const bool odd = d & 1;
#pragma unroll
    for (int mi = 0; mi < 4; ++mi) {
#pragma unroll
      for (int r = 0; r < 4; ++r) {
        const int rr = wr + mi * 16 + lg * 4 + r;
        const int s = (m0 + rr) & 2047;
        float v = acc[mi][ni][r] + bi_;
        if (sec < 2) {
          const float c = fc[s * 32 + i2], sn = fs[s * 32 + i2];
          const float p = __shfl_xor(v, 1);
          v = odd ? (p * sn + v * c) : (v * c - p * sn);
          if (sec == 0) v *= 0.125f;
          smem[rr * 136 + cc] = f2bf(v);
        } else {
          smem[cc * 136 + rr] = f2bf(v);        // transposed for vtc
        }
      }
    }
  }
  __syncthreads();
  // ---- stage 2: coalesced uint4 stores ----
  if (sec < 2) {
    u16* const dst = (sec == 0) ? qr : kr;
#pragma unroll
    for (int it = 0; it < 8; ++it) {
      const int c = it * 256 + tid;
      const int j = c & 7, hh = (c >> 3) & 1, rr = c >> 4;
      const int row = m0 + rr;
      const int bb = row >> 11, ss = row & 2047;
      const uint4 val = *(const uint4*)&smem[rr * 136 + hh * 64 + j * 8];
      *(uint4*)&dst[((size_t)(((bb << 4) + h0 + hh) << 11) + ss) * 64 + j * 8] = val;
    }
  } else {
    const int b16 = (m0 >> 11) << 4;
    const int chbase = (m0 & 2047) >> 6;
#pragma unroll
    for (int it = 0; it < 8; ++it) {
      const int c = it * 256 + tid;
      const int j2 = c & 7;
      const int rr2 = c >> 3;
      const int d = rr2 & 63, hh = (rr2 >> 6) & 1, chk = rr2 >> 7;
      const uint4 val = *(const uint4*)&smem[(hh * 64 + d) * 136 + chk * 64 + j2 * 8];
      *(uint4*)&vtc[(((size_t)(b16 + h0 + hh)) * 32 + chbase + chk) * 4096 + d * 64 + j2 * 8] = val;
    }
  }
}

// ---------------- GEMM (O-proj): BK=64, fp32 out, XCD swizzle ----------------
__global__ __launch_bounds__(256, 2)
void gemm_bt(const u16* __restrict__ A, const u16* __restrict__ Bt,
             const float* __restrict__ bias, float* __restrict__ C,
             int M, int N, int K) {
  __shared__ __align__(16) u16 As[2 * 128 * 32];
  __shared__ __align__(16) u16 Bs[2 * 128 * 32];
  const int nb = N >> 7;
  const int nwg = (M >> 7) * nb;
  const int bid = (int)blockIdx.x;
  const int cpx = nwg >> 3;
  const int swb = (bid & 7) * cpx + (bid >> 3);
  const int m0 = (swb / nb) << 7;
  const int n0 = (swb % nb) << 7;
  const int tid = threadIdx.x;
  const int l = tid & 63, lg = l >> 4, ll = l & 15;
  const int w = tid >> 6;
  const int wr = (w >> 1) << 6, wc = (w & 1) << 6;
  const int srow = tid >> 2, scol = (tid & 3) << 3;
  const u16* ga = A + (size_t)(m0 + srow) * K + scol;
  const u16* gb = Bt + (size_t)(n0 + srow) * K + scol;
  const size_t K64 = (size_t)64 * K;
  u16* const la00 = &As[srow * 32 + scol];
  u16* const la01 = &As[4096 + srow * 32 + scol];
  u16* const la10 = &As[(srow + 64) * 32 + scol];
  u16* const la11 = &As[4096 + (srow + 64) * 32 + scol];
  u16* const lb00 = &Bs[srow * 32 + scol];
  u16* const lb01 = &Bs[4096 + srow * 32 + scol];
  u16* const lb10 = &Bs[(srow + 64) * 32 + scol];
  u16* const lb11 = &Bs[4096 + (srow + 64) * 32 + scol];
  f32x4 acc[4][4] = {};
  for (int kt = 0; kt < K; kt += 64) {
    gload16(ga + kt, la00);       gload16(ga + kt + 32, la01);
    gload16(ga + kt + K64, la10); gload16(ga + kt + K64 + 32, la11);
    gload16(gb + kt, lb00);       gload16(gb + kt + 32, lb01);
    gload16(gb + kt + K64, lb10); gload16(gb + kt + K64 + 32, lb11);
    __syncthreads();
#pragma unroll
    for (int h = 0; h < 2; ++h) {
      bf16x8 a[4], b[4];
#pragma unroll
      for (int i = 0; i < 4; ++i) {
        a[i] = *(const bf16x8*)&As[h * 4096 + (wr + i * 16 + ll) * 32 + lg * 8];
        b[i] = *(const bf16x8*)&Bs[h * 4096 + (wc + i * 16 + ll) * 32 + lg * 8];
      }
#pragma unroll
      for (int mi = 0; mi < 4; ++mi)
#pragma unroll
        for (int ni = 0; ni < 4; ++ni)
          acc[mi][ni] = mfma16(a[mi], b[ni], acc[mi][ni]);
    }
    __syncthreads();
  }
#pragma unroll
  for (int mi = 0; mi < 4; ++mi) {
#pragma unroll
    for (int r = 0; r < 4; ++r) {
      const int row = m0 + wr + mi * 16 + lg * 4 + r;
      float* crow = C + (size_t)row * N + n0 + wc;
#pragma unroll
      for (int ni = 0; ni < 4; ++ni)
        crow[ni * 16 + ll] = acc[mi][ni][r] + bias[n0 + wc + ni * 16 + ll];
    }
  }
}

// ---------------- flash attention v5.1 (R11/R14/R16 verbatim, best known) ----------------
__global__ __launch_bounds__(256, 2)
void attn_k(const u16* __restrict__ qr, const u16* __restrict__ kr,
            const u16* __restrict__ vtc, u16* __restrict__ aout) {
  __shared__ __align__(16) char kvlds[16384];     // [0:8K) K tile, [8K:16K) V^T tile
  const int bi = (int)blockIdx.x;
  const int bh = bi & 31;
  const int qt = (bi < 256) ? (15 - (bi >> 5)) : ((bi - 256) >> 5);
  const int tid = threadIdx.x;
  const int w = tid >> 6, l = tid & 63, hi = l >> 5, ql = l & 31;
  const u16* Q  = qr + (size_t)bh * (2048 * 64);
  const u16* Kp = kr + (size_t)bh * (2048 * 64);
  const int q0w = (qt << 7) + (w << 5);
  const int qg = q0w + ql;
  bf16x8 qf[4];
#pragma unroll
  for (int mi = 0; mi < 4; ++mi)
    qf[mi] = *(const bf16x8*)&Q[(size_t)qg * 64 + mi * 16 + hi * 8];
  const int sr = tid >> 2, sc = (tid & 3) * 32;
  const int wo0 = (sr * 128 + sc) ^ ((sr & 7) << 4);
  const int wo1 = (sr * 128 + sc + 16) ^ ((sr & 7) << 4);
  const char* kga = (const char*)(Kp + (size_t)sr * 64) + sc;                    // + ch*8192
  const char* vga = (const char*)(vtc + (size_t)bh * 32 * 4096) + sr * 128 + sc; // + ch*8192
  const int swz = (ql & 7) << 4;
  f32x16 oa = {}, ob = {};
  float mrow = -1e30f, lp = 0.f;
  const int nch = 2 * qt + 2;
  uint4 sk0 = *(const uint4*)(kga), sk1 = *(const uint4*)(kga + 16);
  uint4 sv0 = *(const uint4*)(vga), sv1 = *(const uint4*)(vga + 16);
  for (int ch = 0; ch < nch; ++ch) {
    asm volatile("s_waitcnt vmcnt(0)" ::: "memory");
    asm volatile("s_barrier" ::: "memory");
    *(uint4*)(kvlds + wo0) = sk0;
    *(uint4*)(kvlds + wo1) = sk1;
    *(uint4*)(kvlds + 8192 + wo0) = sv0;
    *(uint4*)(kvlds + 8192 + wo1) = sv1;
    if (ch + 1 < nch) {
      const size_t kof = (size_t)(ch + 1) * 8192;
      sk0 = *(const uint4*)(kga + kof); sk1 = *(const uint4*)(kga + kof + 16);
      sv0 = *(const uint4*)(vga + kof); sv1 = *(const uint4*)(vga + kof + 16);
    }
    asm volatile("s_waitcnt lgkmcnt(0)" ::: "memory");
    asm volatile("s_barrier" ::: "memory");
    const int kb = ch << 6;
    if (kb > q0w + 31) continue;
    f32x16 s0 = {}, s1 = {};
#pragma unroll
    for (int mi = 0; mi < 4; ++mi) {
      const int cb = mi * 32 + hi * 16;
      const bf16x8 k0 = *(const bf16x8*)(kvlds + ((ql * 128 + cb) ^ swz));
      const bf16x8 k1 = *(const bf16x8*)(kvlds + (((32 + ql) * 128 + cb) ^ swz));
      s0 = mfma32(k0, qf[mi], s0);
      s1 = mfma32(k1, qf[mi], s1);
    }
    if (kb + 63 > q0w) {
#pragma unroll
      for (int r = 0; r < 16; ++r) {
        const int kvo = (r & 3) + 8 * (r >> 2) + 4 * hi;
        if (kb + kvo > qg) s0[r] = -1e30f;
        if (kb + 32 + kvo > qg) s1[r] = -1e30f;
      }
    }
    float mx = s0[0];
#pragma unroll
    for (int r = 1; r < 16; ++r) mx = fmaxf(mx, s0[r]);
#pragma unroll
    for (int r = 0; r < 16; ++r) mx = fmaxf(mx, s1[r]);
    mx = fmaxf(mx, __shfl_xor(mx, 32));
    if (!__all(mx <= mrow + 8.f)) {
      const float mn = fmaxf(mrow, mx);
      const float esc = __expf(mrow - mn);
      mrow = mn;
      lp *= esc;
#pragma unroll
      for (int r = 0; r < 16; ++r) { oa[r] *= esc; ob[r] *= esc; }
    }
    float p0[16], p1[16];
#pragma unroll
    for (int r = 0; r < 16; ++r) {
      p0[r] = __expf(s0[r] - mrow);
      p1[r] = __expf(s1[r] - mrow);
      lp += p0[r] + p1[r];
    }
    bf16x8 pb[4];
#pragma unroll
    for (int s = 0; s < 2; ++s) {
      const float* ps = s ? p1 : p0;
#pragma unroll
      for (int j = 0; j < 2; ++j) {
        const unsigned X0 = pack2(ps[j * 8 + 0], ps[j * 8 + 1]);
        const unsigned X1 = pack2(ps[j * 8 + 2], ps[j * 8 + 3]);
        const unsigned Y0 = pack2(ps[j * 8 + 4], ps[j * 8 + 5]);
        const unsigned Y1 = pack2(ps[j * 8 + 6], ps[j * 8 + 7]);
        const unsigned sX0 = (unsigned)__shfl_xor((int)X0, 32);
        const unsigned sX1 = (unsigned)__shfl_xor((int)X1, 32);
        const unsigned sY0 = (unsigned)__shfl_xor((int)Y0, 32);
        const unsigned sY1 = (unsigned)__shfl_xor((int)Y1, 32);
        union { unsigned u[4]; bf16x8 v; } t;
        t.u[0] = hi ? sY0 : X0;
        t.u[1] = hi ? sY1 : X1;
        t.u[2] = hi ? Y0 : sX0;
        t.u[3] = hi ? Y1 : sX1;
        pb[s * 2 + j] = t.v;
      }
    }
#pragma unroll
    for (int jj = 0; jj < 4; ++jj) {
      const int cb = jj * 32 + hi * 16;
      const bf16x8 va = *(const bf16x8*)(kvlds + 8192 + ((ql * 128 + cb) ^ swz));
      const bf16x8 vb = *(const bf16x8*)(kvlds + 8192 + (((32 + ql) * 128 + cb) ^ swz));
      oa = mfma32(va, pb[jj], oa);
      ob = mfma32(vb, pb[jj], ob);
    }
  }
  lp += __shfl_xor(lp, 32);
  const float inv = 1.0f / lp;
  const int hcol = (bh & 15) << 6;
  const int tok = ((bh >> 4) << 11) + qg;
  unsigned* orow = (unsigned*)(aout + (size_t)tok * 1024 + hcol);
#pragma unroll
  for (int r = 0; r < 16; r += 2) {
    const int d0 = (r & 3) + 8 * (r >> 2) + 4 * hi;
    orow[d0 >> 1]        = pack2(oa[r] * inv, oa[r + 1] * inv);
    orow[(32 + d0) >> 1] = pack2(ob[r] * inv, ob[r + 1] * inv);
  }
}

extern "C" void kernel_launch(void* const* d_in, const int* in_sizes, int n_in,
                              void* d_out, int out_size, void* d_ws, size_t ws_size,
                              hipStream_t stream) {
  const float* x    = (const float*)d_in[0];
  const float* fc   = (const float*)d_in[2];
  const float* fs   = (const float*)d_in[3];
  const float* Wqkv = (const float*)d_in[4];
  const float* bqkv = (const float*)d_in[5];
  const float* Wo   = (const float*)d_in[6];
  const float* bo   = (const float*)d_in[7];
  float* out = (float*)d_out;

  size_t off = 0;
  auto alloc = [&](size_t bytes) {
    void* p = (char*)d_ws + off;
    off += (bytes + 255) & ~(size_t)255;
    return p;
  };
  u16*   xb   = (u16*)  alloc(4096ull * 1024 * 2);   // x bf16
  u16*   wqt  = (u16*)  alloc(3072ull * 1024 * 2);   // W_qkv^T bf16
  u16*   wot  = (u16*)  alloc(1024ull * 1024 * 2);   // W_o^T bf16
  u16*   qr_  = (u16*)  alloc(32ull * 2048 * 64 * 2);// q roped, head-major
  u16*   kr_  = (u16*)  alloc(32ull * 2048 * 64 * 2);// k roped, head-major
  u16*   vtc_ = (u16*)  alloc(32ull * 32 * 4096 * 2);// v^T chunked [bh][ch][d][64]
  u16*   ao_  = (u16*)  alloc(4096ull * 1024 * 2);   // attention out bf16

  prep_kernel<<<dim3(3072), 256, 0, stream>>>(x, xb, Wqkv, wqt, Wo, wot);
  gemm_qkv<<<dim3(32 * 24), 256, 0, stream>>>(xb, wqt, bqkv, fc, fs, qr_, kr_, vtc_);
  attn_k<<<dim3(512), 256, 0, stream>>>(qr_, kr_, vtc_, ao_);
  gemm_bt<<<dim3(32 * 8), 256, 0, stream>>>(ao_, wot, bo, out, 4096, 1024, 1024);
}

// Round 19
// 115.290 us; speedup vs baseline: 1.3895x; 1.0267x over previous
//
#include <hip/hip_runtime.h>
#include <hip/hip_bf16.h>
#include <stdint.h>

typedef unsigned short u16;
typedef __attribute__((ext_vector_type(8))) __bf16 bf16x8;
typedef __attribute__((ext_vector_type(4))) float f32x4;
typedef __attribute__((ext_vector_type(16))) float f32x16;
typedef __attribute__((ext_vector_type(8))) u16 u16x8;

__device__ __forceinline__ u16 f2bf(float f) {
  union { float f; unsigned int u; } v; v.f = f;
  unsigned int r = v.u + 0x7fffu + ((v.u >> 16) & 1u);
  return (u16)(r >> 16);
}
__device__ __forceinline__ unsigned pack2(float lo, float hi) {
  return (unsigned)f2bf(lo) | ((unsigned)f2bf(hi) << 16);
}

__device__ __forceinline__ f32x4 mfma16(bf16x8 a, bf16x8 b, f32x4 c) {
  return __builtin_amdgcn_mfma_f32_16x16x32_bf16(a, b, c, 0, 0, 0);
}
__device__ __forceinline__ f32x16 mfma32(bf16x8 a, bf16x8 b, f32x16 c) {
  return __builtin_amdgcn_mfma_f32_32x32x16_bf16(a, b, c, 0, 0, 0);
}

__device__ __forceinline__ void gload16(const void* g, void* l) {
  __builtin_amdgcn_global_load_lds((const __attribute__((address_space(1))) void*)g,
                                   (__attribute__((address_space(3))) void*)l,
                                   16, 0, 0);
}

// ---------------- fused prep: cast x + transpose-cast Wqkv + transpose-cast Wo ----------------
__global__ __launch_bounds__(256)
void prep_kernel(const float* __restrict__ x, u16* __restrict__ xb,
                 const float* __restrict__ Wqkv, u16* __restrict__ wqt,
                 const float* __restrict__ Wo, u16* __restrict__ wot) {
  __shared__ float tile[64][65];
  const int bid = (int)blockIdx.x;
  if (bid < 2048) {
    const int i = (bid * 256 + (int)threadIdx.x) * 8;
    const float4* p = (const float4*)(x + i);
    float4 a = p[0], b = p[1];
    u16x8 o;
    o[0] = f2bf(a.x); o[1] = f2bf(a.y); o[2] = f2bf(a.z); o[3] = f2bf(a.w);
    o[4] = f2bf(b.x); o[5] = f2bf(b.y); o[6] = f2bf(b.z); o[7] = f2bf(b.w);
    *(u16x8*)(xb + i) = o;
    return;
  }
  const float* in;
  u16* out;
  int R, Ccols, c0, r0;
  if (bid < 2816) {
    const int t = bid - 2048;            // 48 x 16
    in = Wqkv; out = wqt; R = 1024; Ccols = 3072;
    c0 = (t % 48) << 6; r0 = (t / 48) << 6;
  } else {
    const int t = bid - 2816;            // 16 x 16
    in = Wo; out = wot; R = 1024; Ccols = 1024;
    c0 = (t % 16) << 6; r0 = (t / 16) << 6;
  }
  const int tx = threadIdx.x & 63, ty = threadIdx.x >> 6;
#pragma unroll
  for (int i = ty; i < 64; i += 4)
    tile[i][tx] = in[(size_t)(r0 + i) * Ccols + c0 + tx];
  __syncthreads();
#pragma unroll
  for (int i = ty; i < 64; i += 4)
    out[(size_t)(c0 + i) * R + r0 + tx] = f2bf(tile[tx][i]);
}

// ---------------- QKV GEMM, BK=64, fused bias+RoPE+head-split epilogue ----------------
// V section writes chunked-transposed vtc[bh][ch][64 d][64 s] directly (R14).
// XCD-aware block swizzle (T1): grid 768 = 8 XCDs x 96 contiguous blocks.
__global__ __launch_bounds__(256, 3)
void gemm_qkv(const u16* __restrict__ A, const u16* __restrict__ Bt,
              const float* __restrict__ bias,
              const float* __restrict__ fc, const float* __restrict__ fs,
              u16* __restrict__ qr, u16* __restrict__ kr, u16* __restrict__ vtc) {
  const int K = 1024;
  __shared__ __align__(16) u16 smem[128 * 136];
  u16* const As = smem;
  u16* const Bs = smem + 8192;
  const int bid = (int)blockIdx.x;
  const int swb = (bid & 7) * 96 + (bid >> 3);   // bijective XCD swizzle (768 % 8 == 0)
  const int m0 = (swb / 24) << 7;
  const int n0 = (swb % 24) << 7;
  const int tid = threadIdx.x;
  const int l = tid & 63, lg = l >> 4, ll = l & 15;
  const int w = tid >> 6;
  const int wr = (w >> 1) << 6, wc = (w & 1) << 6;
  const int srow = tid >> 2, scol = (tid & 3) << 3;
  const u16* ga = A + (size_t)(m0 + srow) * K + scol;
  const u16* gb = Bt + (size_t)(n0 + srow) * K + scol;
  const size_t K64 = (size_t)64 * K;
  u16* const la00 = &As[srow * 32 + scol];
  u16* const la01 = &As[4096 + srow * 32 + scol];
  u16* const la10 = &As[(srow + 64) * 32 + scol];
  u16* const la11 = &As[4096 + (srow + 64) * 32 + scol];
  u16* const lb00 = &Bs[srow * 32 + scol];
  u16* const lb01 = &Bs[4096 + srow * 32 + scol];
  u16* const lb10 = &Bs[(srow + 64) * 32 + scol];
  u16* const lb11 = &Bs[4096 + (srow + 64) * 32 + scol];
  f32x4 acc[4][4] = {};
  for (int kt = 0; kt < K; kt += 64) {
    gload16(ga + kt, la00);       gload16(ga + kt + 32, la01);
    gload16(ga + kt + K64, la10); gload16(ga + kt + K64 + 32, la11);
    gload16(gb + kt, lb00);       gload16(gb + kt + 32, lb01);
    gload16(gb + kt + K64, lb10); gload16(gb + kt + K64 + 32, lb11);
    __syncthreads();
#pragma unroll
    for (int h = 0; h < 2; ++h) {
      bf16x8 a[4], b[4];
#pragma unroll
      for (int i = 0; i < 4; ++i) {
        a[i] = *(const bf16x8*)&As[h * 4096 + (wr + i * 16 + ll) * 32 + lg * 8];
        b[i] = *(const bf16x8*)&Bs[h * 4096 + (wc + i * 16 + ll) * 32 + lg * 8];
      }
#pragma unroll
      for (int mi = 0; mi < 4; ++mi)
#pragma unroll
        for (int ni = 0; ni < 4; ++ni)
          acc[mi][ni] = mfma16(a[mi], b[ni], acc[mi][ni]);
    }
    __syncthreads();
  }
  // ---- stage 1: bias (+rope for Q/K) -> LDS tile ----
  const int sec = n0 >> 10;                       // 0=Q, 1=K, 2=V
  const int h0 = (n0 & 1023) >> 6;
#pragma unroll
  for (int ni = 0; ni < 4; ++ni) {
    const int cc = wc + ni * 16 + ll;
    const int n = n0 + cc;
    const int d = n & 63;
    const float bi_ = bias[n];
    const int i2 = d >> 1;
    const bool odd = d & 1;
#pragma unroll
    for (int mi = 0; mi < 4; ++mi) {
#pragma unroll
      for (int r = 0; r < 4; ++r) {
        const int rr = wr + mi * 16 + lg * 4 + r;
        const int s = (m0 + rr) & 2047;
        float v = acc[mi][ni][r] + bi_;
        if (sec < 2) {
          const float c = fc[s * 32 + i2], sn = fs[s * 32 + i2];
          const float p = __shfl_xor(v, 1);
          v = odd ? (p * sn + v * c) : (v * c - p * sn);
          if (sec == 0) v *= 0.125f;
          smem[rr * 136 + cc] = f2bf(v);
        } else {
          smem[cc * 136 + rr] = f2bf(v);        // transposed for vtc
        }
      }
    }
  }
  __syncthreads();
  // ---- stage 2: coalesced uint4 stores ----
  if (sec < 2) {
    u16* const dst = (sec == 0) ? qr : kr;
#pragma unroll
    for (int it = 0; it < 8; ++it) {
      const int c = it * 256 + tid;
      const int j = c & 7, hh = (c >> 3) & 1, rr = c >> 4;
      const int row = m0 + rr;
      const int bb = row >> 11, ss = row & 2047;
      const uint4 val = *(const uint4*)&smem[rr * 136 + hh * 64 + j * 8];
      *(uint4*)&dst[((size_t)(((bb << 4) + h0 + hh) << 11) + ss) * 64 + j * 8] = val;
    }
  } else {
    const int b16 = (m0 >> 11) << 4;
    const int chbase = (m0 & 2047) >> 6;
#pragma unroll
    for (int it = 0; it < 8; ++it) {
      const int c = it * 256 + tid;
      const int j2 = c & 7;
      const int rr2 = c >> 3;
      const int d = rr2 & 63, hh = (rr2 >> 6) & 1, chk = rr2 >> 7;
      const uint4 val = *(const uint4*)&smem[(hh * 64 + d) * 136 + chk * 64 + j2 * 8];
      *(uint4*)&vtc[(((size_t)(b16 + h0 + hh)) * 32 + chbase + chk) * 4096 + d * 64 + j2 * 8] = val;
    }
  }
}

// ---------------- GEMM (O-proj): 64M x 128N tile, BK=64, fp32 out, XCD swizzle ----------------
// Grid 512 = 2 blocks/CU (was 256 = 1/CU = 1 wave/SIMD, zero TLP). Each wave
// owns 32 rows x 64 cols (acc[2][4]). A-tile halves to [2][64][32]; B-path,
// staging pattern, and epilogue unchanged from the verified 128x128 kernel.
__global__ __launch_bounds__(256, 2)
void gemm_bt(const u16* __restrict__ A, const u16* __restrict__ Bt,
             const float* __restrict__ bias, float* __restrict__ C,
             int M, int N, int K) {
  __shared__ __align__(16) u16 As[2 * 64 * 32];    // 8 KB
  __shared__ __align__(16) u16 Bs[2 * 128 * 32];   // 16 KB
  const int nb = N >> 7;
  const int nwg = (M >> 6) * nb;
  const int bid = (int)blockIdx.x;
  const int cpx = nwg >> 3;                        // grid % 8 == 0
  const int swb = (bid & 7) * cpx + (bid >> 3);
  const int m0 = (swb / nb) << 6;
  const int n0 = (swb % nb) << 7;
  const int tid = threadIdx.x;
  const int l = tid & 63, lg = l >> 4, ll = l & 15;
  const int w = tid >> 6;
  const int wr = (w >> 1) << 5;                    // 0 or 32
  const int wc = (w & 1) << 6;                     // 0 or 64
  const int srow = tid >> 2, scol = (tid & 3) << 3;
  const u16* ga = A + (size_t)(m0 + srow) * K + scol;
  const u16* gb = Bt + (size_t)(n0 + srow) * K + scol;
  const size_t K64 = (size_t)64 * K;
  u16* const la00 = &As[srow * 32 + scol];
  u16* const la01 = &As[2048 + srow * 32 + scol];
  u16* const lb00 = &Bs[srow * 32 + scol];
  u16* const lb01 = &Bs[4096 + srow * 32 + scol];
  u16* const lb10 = &Bs[(srow + 64) * 32 + scol];
  u16* const lb11 = &Bs[4096 + (srow + 64) * 32 + scol];
  f32x4 acc[2][4] = {};
  for (int kt = 0; kt < K; kt += 64) {
    gload16(ga + kt, la00);       gload16(ga + kt + 32, la01);
    gload16(gb + kt, lb00);       gload16(gb + kt + 32, lb01);
    gload16(gb + kt + K64, lb10); gload16(gb + kt + K64 + 32, lb11);
    __syncthreads();
#pragma unroll
    for (int h = 0; h < 2; ++h) {
      bf16x8 a[2], b[4];
#pragma unroll
      for (int i = 0; i < 2; ++i)
        a[i] = *(const bf16x8*)&As[h * 2048 + (wr + i * 16 + ll) * 32 + lg * 8];
#pragma unroll
      for (int i = 0; i < 4; ++i)
        b[i] = *(const bf16x8*)&Bs[h * 4096 + (wc + i * 16 + ll) * 32 + lg * 8];
#pragma unroll
      for (int mi = 0; mi < 2; ++mi)
#pragma unroll
        for (int ni = 0; ni < 4; ++ni)
          acc[mi][ni] = mfma16(a[mi], b[ni], acc[mi][ni]);
    }
    __syncthreads();
  }
#pragma unroll
  for (int mi = 0; mi < 2; ++mi) {
#pragma unroll
    for (int r = 0; r < 4; ++r) {
      const int row = m0 + wr + mi * 16 + lg * 4 + r;
      float* crow = C + (size_t)row * N + n0 + wc;
#pragma unroll
      for (int ni = 0; ni < 4; ++ni)
        crow[ni * 16 + ll] = acc[mi][ni][r] + bias[n0 + wc + ni * 16 + ll];
    }
  }
}

// ---------------- flash attention v5.1 (R11/R14/R16 verbatim, best known) ----------------
__global__ __launch_bounds__(256, 2)
void attn_k(const u16* __restrict__ qr, const u16* __restrict__ kr,
            const u16* __restrict__ vtc, u16* __restrict__ aout) {
  __shared__ __align__(16) char kvlds[16384];     // [0:8K) K tile, [8K:16K) V^T tile
  const int bi = (int)blockIdx.x;
  const int bh = bi & 31;
  const int qt = (bi < 256) ? (15 - (bi >> 5)) : ((bi - 256) >> 5);
  const int tid = threadIdx.x;
  const int w = tid >> 6, l = tid & 63, hi = l >> 5, ql = l & 31;
  const u16* Q  = qr + (size_t)bh * (2048 * 64);
  const u16* Kp = kr + (size_t)bh * (2048 * 64);
  const int q0w = (qt << 7) + (w << 5);
  const int qg = q0w + ql;
  bf16x8 qf[4];
#pragma unroll
  for (int mi = 0; mi < 4; ++mi)
    qf[mi] = *(const bf16x8*)&Q[(size_t)qg * 64 + mi * 16 + hi * 8];
  const int sr = tid >> 2, sc = (tid & 3) * 32;
  const int wo0 = (sr * 128 + sc) ^ ((sr & 7) << 4);
  const int wo1 = (sr * 128 + sc + 16) ^ ((sr & 7) << 4);
  const char* kga = (const char*)(Kp + (size_t)sr * 64) + sc;                    // + ch*8192
  const char* vga = (const char*)(vtc + (size_t)bh * 32 * 4096) + sr * 128 + sc; // + ch*8192
  const int swz = (ql & 7) << 4;
  f32x16 oa = {}, ob = {};
  float mrow = -1e30f, lp = 0.f;
  const int nch = 2 * qt + 2;
  uint4 sk0 = *(const uint4*)(kga), sk1 = *(const uint4*)(kga + 16);
  uint4 sv0 = *(const uint4*)(vga), sv1 = *(const uint4*)(vga + 16);
  for (int ch = 0; ch < nch; ++ch) {
    asm volatile("s_waitcnt vmcnt(0)" ::: "memory");
    asm volatile("s_barrier" ::: "memory");
    *(uint4*)(kvlds + wo0) = sk0;
    *(uint4*)(kvlds + wo1) = sk1;
    *(uint4*)(kvlds + 8192 + wo0) = sv0;
    *(uint4*)(kvlds + 8192 + wo1) = sv1;
    if (ch + 1 < nch) {
      const size_t kof = (size_t)(ch + 1) * 8192;
      sk0 = *(const uint4*)(kga + kof); sk1 = *(const uint4*)(kga + kof + 16);
      sv0 = *(const uint4*)(vga + kof); sv1 = *(const uint4*)(vga + kof + 16);
    }
    asm volatile("s_waitcnt lgkmcnt(0)" ::: "memory");
    asm volatile("s_barrier" ::: "memory");
    const int kb = ch << 6;
    if (kb > q0w + 31) continue;
    f32x16 s0 = {}, s1 = {};
#pragma unroll
    for (int mi = 0; mi < 4; ++mi) {
      const int cb = mi * 32 + hi * 16;
      const bf16x8 k0 = *(const bf16x8*)(kvlds + ((ql * 128 + cb) ^ swz));
      const bf16x8 k1 = *(const bf16x8*)(kvlds + (((32 + ql) * 128 + cb) ^ swz));
      s0 = mfma32(k0, qf[mi], s0);
      s1 = mfma32(k1, qf[mi], s1);
    }
    if (kb + 63 > q0w) {
#pragma unroll
      for (int r = 0; r < 16; ++r) {
        const int kvo = (r & 3) + 8 * (r >> 2) + 4 * hi;
        if (kb + kvo > qg) s0[r] = -1e30f;
        if (kb + 32 + kvo > qg) s1[r] = -1e30f;
      }
    }
    float mx = s0[0];
#pragma unroll
    for (int r = 1; r < 16; ++r) mx = fmaxf(mx, s0[r]);
#pragma unroll
    for (int r = 0; r < 16; ++r) mx = fmaxf(mx, s1[r]);
    mx = fmaxf(mx, __shfl_xor(mx, 32));
    if (!__all(mx <= mrow + 8.f)) {
      const float mn = fmaxf(mrow, mx);
      const float esc = __expf(mrow - mn);
      mrow = mn;
      lp *= esc;
#pragma unroll
      for (int r = 0; r < 16; ++r) { oa[r] *= esc; ob[r] *= esc; }
    }
    float p0[16], p1[16];
#pragma unroll
    for (int r = 0; r < 16; ++r) {
      p0[r] = __expf(s0[r] - mrow);
      p1[r] = __expf(s1[r] - mrow);
      lp += p0[r] + p1[r];
    }
    bf16x8 pb[4];
#pragma unroll
    for (int s = 0; s < 2; ++s) {
      const float* ps = s ? p1 : p0;
#pragma unroll
      for (int j = 0; j < 2; ++j) {
        const unsigned X0 = pack2(ps[j * 8 + 0], ps[j * 8 + 1]);
        const unsigned X1 = pack2(ps[j * 8 + 2], ps[j * 8 + 3]);
        const unsigned Y0 = pack2(ps[j * 8 + 4], ps[j * 8 + 5]);
        const unsigned Y1 = pack2(ps[j * 8 + 6], ps[j * 8 + 7]);
        const unsigned sX0 = (unsigned)__shfl_xor((int)X0, 32);
        const unsigned sX1 = (unsigned)__shfl_xor((int)X1, 32);
        const unsigned sY0 = (unsigned)__shfl_xor((int)Y0, 32);
        const unsigned sY1 = (unsigned)__shfl_xor((int)Y1, 32);
        union { unsigned u[4]; bf16x8 v; } t;
        t.u[0] = hi ? sY0 : X0;
        t.u[1] = hi ? sY1 : X1;
        t.u[2] = hi ? Y0 : sX0;
        t.u[3] = hi ? Y1 : sX1;
        pb[s * 2 + j] = t.v;
      }
    }
#pragma unroll
    for (int jj = 0; jj < 4; ++jj) {
      const int cb = jj * 32 + hi * 16;
      const bf16x8 va = *(const bf16x8*)(kvlds + 8192 + ((ql * 128 + cb) ^ swz));
      const bf16x8 vb = *(const bf16x8*)(kvlds + 8192 + (((32 + ql) * 128 + cb) ^ swz));
      oa = mfma32(va, pb[jj], oa);
      ob = mfma32(vb, pb[jj], ob);
    }
  }
  lp += __shfl_xor(lp, 32);
  const float inv = 1.0f / lp;
  const int hcol = (bh & 15) << 6;
  const int tok = ((bh >> 4) << 11) + qg;
  unsigned* orow = (unsigned*)(aout + (size_t)tok * 1024 + hcol);
#pragma unroll
  for (int r = 0; r < 16; r += 2) {
    const int d0 = (r & 3) + 8 * (r >> 2) + 4 * hi;
    orow[d0 >> 1]        = pack2(oa[r] * inv, oa[r + 1] * inv);
    orow[(32 + d0) >> 1] = pack2(ob[r] * inv, ob[r + 1] * inv);
  }
}

extern "C" void kernel_launch(void* const* d_in, const int* in_sizes, int n_in,
                              void* d_out, int out_size, void* d_ws, size_t ws_size,
                              hipStream_t stream) {
  const float* x    = (const float*)d_in[0];
  const float* fc   = (const float*)d_in[2];
  const float* fs   = (const float*)d_in[3];
  const float* Wqkv = (const float*)d_in[4];
  const float* bqkv = (const float*)d_in[5];
  const float* Wo   = (const float*)d_in[6];
  const float* bo   = (const float*)d_in[7];
  float* out = (float*)d_out;

  size_t off = 0;
  auto alloc = [&](size_t bytes) {
    void* p = (char*)d_ws + off;
    off += (bytes + 255) & ~(size_t)255;
    return p;
  };
  u16*   xb   = (u16*)  alloc(4096ull * 1024 * 2);   // x bf16
  u16*   wqt  = (u16*)  alloc(3072ull * 1024 * 2);   // W_qkv^T bf16
  u16*   wot  = (u16*)  alloc(1024ull * 1024 * 2);   // W_o^T bf16
  u16*   qr_  = (u16*)  alloc(32ull * 2048 * 64 * 2);// q roped, head-major
  u16*   kr_  = (u16*)  alloc(32ull * 2048 * 64 * 2);// k roped, head-major
  u16*   vtc_ = (u16*)  alloc(32ull * 32 * 4096 * 2);// v^T chunked [bh][ch][d][64]
  u16*   ao_  = (u16*)  alloc(4096ull * 1024 * 2);   // attention out bf16

  prep_kernel<<<dim3(3072), 256, 0, stream>>>(x, xb, Wqkv, wqt, Wo, wot);
  gemm_qkv<<<dim3(32 * 24), 256, 0, stream>>>(xb, wqt, bqkv, fc, fs, qr_, kr_, vtc_);
  attn_k<<<dim3(512), 256, 0, stream>>>(qr_, kr_, vtc_, ao_);
  gemm_bt<<<dim3(512), 256, 0, stream>>>(ao_, wot, bo, out, 4096, 1024, 1024);
}